// Round 2
// baseline (290.495 us; speedup 1.0000x reference)
//
#include <hip/hip_runtime.h>
#include <hip/hip_bf16.h>
#include <math.h>

namespace {

constexpr int B  = 4;
constexpr int N  = 2048;
constexpr int F0 = 6;
constexpr int F  = 64;
constexpr int DK = 16;
constexpr float EPS = 1e-5f;
constexpr int NCH0 = 16;  // n-chunks, layer-0 adjacency
constexpr int NCH  = 4;   // n-chunks, big layers

// ---------------- squared norms per node ----------------
template<int D>
__global__ __launch_bounds__(256) void k_sqnorm(const float* __restrict__ x,
                                                float* __restrict__ sqn) {
  int idx = blockIdx.x * 256 + threadIdx.x;
  if (idx >= B * N) return;
  int b = idx >> 11;
  int n = idx & (N - 1);
  const float* xp = x + (size_t)b * D * N + n;
  float s = 0.f;
#pragma unroll
  for (int d = 0; d < D; ++d) { float v = xp[(size_t)d * N]; s = fmaf(v, v, s); }
  sqn[idx] = s;
}

// ---------------- layer-0 fused adjacency + deg + adj_msg (D=F=6) ----------------
__global__ __launch_bounds__(256) void k_adj0(const float* __restrict__ x,
                                              const float* __restrict__ sqn,
                                              const float* __restrict__ sigma,
                                              float* __restrict__ pdmsg,  // (NCH0,B,F0,N)
                                              float* __restrict__ pdeg) { // (NCH0,B,N)
  constexpr int NC = N / NCH0;  // 128
  int t = threadIdx.x;
  int m = blockIdx.x * 256 + t;
  int ch = blockIdx.y, b = blockIdx.z;
  float sg = sigma[0];
  float inv_s2 = 1.f / (sg * sg);
  const float* xb = x + (size_t)b * F0 * N;
  float pm[F0];
#pragma unroll
  for (int d = 0; d < F0; ++d) pm[d] = xb[(size_t)d * N + m];
  float sqm = sqn[b * N + m];
  float acc[F0] = {};
  float deg = 0.f;
  __shared__ __align__(16) float xt[F0][64];
  __shared__ float st[64];
  int n0 = ch * NC;
  for (int nt = 0; nt < NC; nt += 64) {
    __syncthreads();
    for (int e = t; e < F0 * 64; e += 256) {
      int d = e >> 6, nn = e & 63;
      xt[d][nn] = xb[(size_t)d * N + n0 + nt + nn];
    }
    if (t < 64) st[t] = sqn[b * N + n0 + nt + t];
    __syncthreads();
#pragma unroll 2
    for (int nn = 0; nn < 64; ++nn) {
      float pn[F0];
#pragma unroll
      for (int d = 0; d < F0; ++d) pn[d] = xt[d][nn];
      float g = 0.f;
#pragma unroll
      for (int d = 0; d < F0; ++d) g = fmaf(pm[d], pn[d], g);
      float dist = fmaxf(sqm + st[nn] - 2.f * g, 0.f);
      float a = __expf(-dist * inv_s2);
      deg += a;
#pragma unroll
      for (int d = 0; d < F0; ++d) acc[d] = fmaf(a, pn[d], acc[d]);
    }
  }
  size_t base = (size_t)ch * B + b;
#pragma unroll
  for (int d = 0; d < F0; ++d) pdmsg[(base * F0 + d) * N + m] = acc[d];
  pdeg[base * N + m] = deg;
}

// ---------------- big-layer fused adjacency + deg + adj_msg (D=16, F=64) ----------------
__global__ __launch_bounds__(256) void k_adjmsg(const float* __restrict__ proj,
                                                const float* __restrict__ sqn,
                                                const float* __restrict__ V,
                                                float* __restrict__ pdmsg,  // (NCH,B,F,N)
                                                float* __restrict__ pdeg) { // (NCH,B,N)
  constexpr int D = DK;
  constexpr int NC = N / NCH;  // 512
  int t = threadIdx.x;
  int tm = t & 15, tf = t >> 4;
  int m4 = tm * 4, f4 = tf * 4, n4 = tf * 4;
  int M0 = blockIdx.x * 64;
  int ch = blockIdx.y, b = blockIdx.z;
  int n0 = ch * NC;
  const float* pb = proj + (size_t)b * D * N;
  const float* vb = V + (size_t)b * F * N;
  const float* sq = sqn + (size_t)b * N;

  __shared__ __align__(16) float pmS[D][64];
  __shared__ float sqmS[64];
  __shared__ __align__(16) float pnS[D][64];
  __shared__ float sqnS[64];
  __shared__ __align__(16) float adjS[64][64];
  __shared__ __align__(16) float vtS[64][65];  // odd pad: conflict-free scalar reads/writes
  __shared__ float degS[64][17];

  // stage m-tile proj + norms (once)
  {
    int d = t >> 4, mq = (t & 15) * 4;
    *(float4*)&pmS[d][mq] = *(const float4*)&pb[(size_t)d * N + M0 + mq];
  }
  if (t < 64) sqmS[t] = sq[M0 + t];
  __syncthreads();
  float pmr[D][4];
#pragma unroll
  for (int d = 0; d < D; ++d) *(float4*)pmr[d] = *(const float4*)&pmS[d][m4];
  float sqmr[4];
#pragma unroll
  for (int j = 0; j < 4; ++j) sqmr[j] = sqmS[m4 + j];

  float acc[4][4] = {};
  float pd[4] = {};

  for (int nt = 0; nt < NC; nt += 64) {
    __syncthreads();
    {  // stage proj n-tile (256 float4)
      int d = t >> 4, nq = (t & 15) * 4;
      *(float4*)&pnS[d][nq] = *(const float4*)&pb[(size_t)d * N + n0 + nt + nq];
    }
    if (t < 64) sqnS[t] = sq[n0 + nt + t];
#pragma unroll
    for (int r = 0; r < 4; ++r) {  // stage V transposed (1024 float4)
      int e = r * 256 + t;
      int f = e >> 4, nq = (e & 15) * 4;
      float4 v4 = *(const float4*)&vb[(size_t)f * N + n0 + nt + nq];
      vtS[nq + 0][f] = v4.x;
      vtS[nq + 1][f] = v4.y;
      vtS[nq + 2][f] = v4.z;
      vtS[nq + 3][f] = v4.w;
    }
    __syncthreads();
    // gram 4x4 + exp -> adj tile
    float g[4][4] = {};
#pragma unroll 4
    for (int d = 0; d < D; ++d) {
      float bn[4];
      *(float4*)bn = *(const float4*)&pnS[d][n4];
#pragma unroll
      for (int j = 0; j < 4; ++j)
#pragma unroll
        for (int k = 0; k < 4; ++k) g[j][k] = fmaf(pmr[d][j], bn[k], g[j][k]);
    }
#pragma unroll
    for (int k = 0; k < 4; ++k) {
      float row[4];
#pragma unroll
      for (int j = 0; j < 4; ++j) {
        float dist = fmaxf(sqmr[j] + sqnS[n4 + k] - 2.f * g[j][k], 0.f);
        float a = __expf(-dist);
        row[j] = a;
        pd[j] += a;
      }
      *(float4*)&adjS[n4 + k][m4] = *(float4*)row;
    }
    __syncthreads();
    // PV: acc[i][j] += sum_n vt[n][f4+i] * adj[n][m4+j]
#pragma unroll 8
    for (int n = 0; n < 64; ++n) {
      float aa[4];
      *(float4*)aa = *(const float4*)&adjS[n][m4];
      float v0 = vtS[n][f4 + 0], v1 = vtS[n][f4 + 1];
      float v2 = vtS[n][f4 + 2], v3 = vtS[n][f4 + 3];
#pragma unroll
      for (int j = 0; j < 4; ++j) {
        acc[0][j] = fmaf(v0, aa[j], acc[0][j]);
        acc[1][j] = fmaf(v1, aa[j], acc[1][j]);
        acc[2][j] = fmaf(v2, aa[j], acc[2][j]);
        acc[3][j] = fmaf(v3, aa[j], acc[3][j]);
      }
    }
  }
  // deg reduce across the 16 tf-groups
#pragma unroll
  for (int j = 0; j < 4; ++j) degS[m4 + j][tf] = pd[j];
  __syncthreads();
  if (t < 64) {
    float s = 0.f;
#pragma unroll
    for (int q = 0; q < 16; ++q) s += degS[t][q];
    pdeg[((size_t)ch * B + b) * N + M0 + t] = s;
  }
  float* pdm = pdmsg + ((size_t)ch * B + b) * F * N;
#pragma unroll
  for (int i = 0; i < 4; ++i) {
    *(float4*)&pdm[(size_t)(f4 + i) * N + M0 + m4] =
        make_float4(acc[i][0], acc[i][1], acc[i][2], acc[i][3]);
  }
}

// ---------------- chunk-combine + gopconv epilogue ----------------
template<int FIN, int NCHt>
__global__ __launch_bounds__(256) void k_gopconv(const float* __restrict__ X,
                                                 const float* __restrict__ pdmsg,
                                                 const float* __restrict__ pdeg,
                                                 const float* __restrict__ W,     // (64,2*FIN)
                                                 const float* __restrict__ bias,  // (64)
                                                 const float* __restrict__ Wres,  // (64,FIN)
                                                 const float* __restrict__ bres,  // (64)
                                                 float* __restrict__ out) {       // (B,64,N)
  int t = threadIdx.x;
  int m = blockIdx.x * 64 + (t & 63);
  int og = __builtin_amdgcn_readfirstlane(t >> 6);  // wave-uniform -> scalar W loads
  int b = blockIdx.y;
  float deg = 0.f;
#pragma unroll
  for (int c = 0; c < NCHt; ++c) deg += pdeg[((size_t)c * B + b) * N + m];
  float cacc[16], racc[16];
#pragma unroll
  for (int k = 0; k < 16; ++k) {
    cacc[k] = bias[og * 16 + k];
    racc[k] = bres[og * 16 + k];
  }
  for (int f = 0; f < FIN; ++f) {
    float x = X[((size_t)b * FIN + f) * N + m];
    float dm = 0.f;
#pragma unroll
    for (int c = 0; c < NCHt; ++c) dm += pdmsg[(((size_t)c * B + b) * FIN + f) * N + m];
    float c0 = x * deg;
#pragma unroll
    for (int k = 0; k < 16; ++k) {
      int o = og * 16 + k;
      cacc[k] = fmaf(W[(size_t)o * 2 * FIN + f], c0, cacc[k]);
      cacc[k] = fmaf(W[(size_t)o * 2 * FIN + FIN + f], dm, cacc[k]);
      racc[k] = fmaf(Wres[(size_t)o * FIN + f], x, racc[k]);
    }
  }
#pragma unroll
  for (int k = 0; k < 16; ++k) {
    out[((size_t)b * F + og * 16 + k) * N + m] = fmaxf(cacc[k], 0.f) + racc[k];
  }
}

// ---------------- spatialnorm stats (mean/rstd over node dim) ----------------
__global__ __launch_bounds__(256) void k_stats(const float* __restrict__ emb,
                                               float* __restrict__ mean,
                                               float* __restrict__ rstd) {
  int row = blockIdx.x;  // b*F + f
  const float* p = emb + (size_t)row * N;
  int t = threadIdx.x;
  float s = 0.f, s2 = 0.f;
  for (int i = t; i < N; i += 256) {
    float v = p[i];
    s += v;
    s2 = fmaf(v, v, s2);
  }
  __shared__ float rs[256], rq[256];
  rs[t] = s;
  rq[t] = s2;
  __syncthreads();
  for (int off = 128; off > 0; off >>= 1) {
    if (t < off) { rs[t] += rs[t + off]; rq[t] += rq[t + off]; }
    __syncthreads();
  }
  if (t == 0) {
    float mn = rs[0] / N;
    float var = rq[0] / N - mn * mn;
    mean[row] = mn;
    rstd[row] = rsqrtf(var + EPS);
  }
}

__global__ __launch_bounds__(256) void k_snorm(const float* __restrict__ emb,
                                               const float* __restrict__ mean,
                                               const float* __restrict__ rstd,
                                               float* __restrict__ Vout) {
  int idx = blockIdx.x * 256 + threadIdx.x;  // float4 index
  if (idx >= B * F * N / 4) return;
  int row = idx / (N / 4);
  float4 v = ((const float4*)emb)[idx];
  float mn = mean[row], rs = rstd[row];
  float4 o;
  o.x = (v.x - mn) * rs;
  o.y = (v.y - mn) * rs;
  o.z = (v.z - mn) * rs;
  o.w = (v.w - mn) * rs;
  ((float4*)Vout)[idx] = o;
}

// ---------------- proj = adj_proj[i] @ emb ----------------
__global__ __launch_bounds__(256) void k_proj(const float* __restrict__ ap,   // (DK,F)
                                              const float* __restrict__ emb,  // (B,F,N)
                                              float* __restrict__ proj) {     // (B,DK,N)
  int n = blockIdx.x * 256 + threadIdx.x;
  int d = blockIdx.y, b = blockIdx.z;
  const float* e = emb + (size_t)b * F * N + n;
  float s = 0.f;
#pragma unroll
  for (int f = 0; f < F; ++f) s = fmaf(ap[d * F + f], e[(size_t)f * N], s);
  proj[((size_t)b * DK + d) * N + n] = s;
}

// ---------------- readout: pool + instance-norm + fcl + sigmoid ----------------
__global__ __launch_bounds__(256) void k_readout(const float* __restrict__ emb,
                                                 const float* __restrict__ fw,
                                                 const float* __restrict__ fb,
                                                 float* __restrict__ out) {
  int b = blockIdx.x, t = threadIdx.x;
  int f = t & 63, part = t >> 6;
  const float* p = emb + ((size_t)b * F + f) * N;
  float s = 0.f;
  for (int i = part * (N / 4); i < (part + 1) * (N / 4); ++i) s += p[i];
  __shared__ float red[4][64];
  red[part][f] = s;
  __syncthreads();
  if (t == 0) {
    float pooled[64];
    float mn = 0.f;
    for (int q = 0; q < 64; ++q) {
      float po = (red[0][q] + red[1][q] + red[2][q] + red[3][q]) / (float)N;
      pooled[q] = po;
      mn += po;
    }
    mn /= 64.f;
    float var = 0.f;
    for (int q = 0; q < 64; ++q) {
      float d2 = pooled[q] - mn;
      var = fmaf(d2, d2, var);
    }
    var /= 64.f;
    float rs = rsqrtf(var + EPS);
    float lg = fb[0];
    for (int q = 0; q < 64; ++q) lg = fmaf((pooled[q] - mn) * rs, fw[q], lg);
    out[b] = 1.f / (1.f + __expf(-lg));
  }
}

}  // namespace

extern "C" void kernel_launch(void* const* d_in, const int* in_sizes, int n_in,
                              void* d_out, int out_size, void* d_ws, size_t ws_size,
                              hipStream_t stream) {
  const float* emb_in   = (const float*)d_in[0];
  const float* sigma    = (const float*)d_in[1];
  const float* fst_w    = (const float*)d_in[2];
  const float* fst_b    = (const float*)d_in[3];
  const float* fst_wres = (const float*)d_in[4];
  const float* fst_bres = (const float*)d_in[5];
  const float* adj_proj = (const float*)d_in[6];
  const float* w        = (const float*)d_in[7];
  const float* bw       = (const float*)d_in[8];
  const float* wres     = (const float*)d_in[9];
  const float* bres     = (const float*)d_in[10];
  const float* fcl_w    = (const float*)d_in[11];
  const float* fcl_b    = (const float*)d_in[12];

  float* ws = (float*)d_ws;
  float* sqn   = ws;  ws += B * N;
  float* pdeg  = ws;  ws += NCH0 * B * N;
  float* pdmsg = ws;  ws += NCH * B * F * N;   // >= NCH0*B*F0*N
  float* embA  = ws;  ws += B * F * N;
  float* embB  = ws;  ws += B * F * N;
  float* Vb    = ws;  ws += B * F * N;
  float* projb = ws;  ws += B * DK * N;
  float* meanb = ws;  ws += B * F;
  float* rstdb = ws;  ws += B * F;

  // ---- layer 0 (input adjacency with sigma) ----
  k_sqnorm<F0><<<dim3(B * N / 256), 256, 0, stream>>>(emb_in, sqn);
  k_adj0<<<dim3(N / 256, NCH0, B), 256, 0, stream>>>(emb_in, sqn, sigma, pdmsg, pdeg);
  k_gopconv<F0, NCH0><<<dim3(N / 64, B), 256, 0, stream>>>(
      emb_in, pdmsg, pdeg, fst_w, fst_b, fst_wres, fst_bres, embA);

  // ---- layers 1..2 (learned adjacency) ----
  const float* src = embA;
  float* dst = embB;
  for (int i = 0; i < 2; ++i) {
    k_proj<<<dim3(N / 256, DK, B), 256, 0, stream>>>(adj_proj + (size_t)i * DK * F, src, projb);
    k_sqnorm<DK><<<dim3(B * N / 256), 256, 0, stream>>>(projb, sqn);
    k_stats<<<dim3(B * F), 256, 0, stream>>>(src, meanb, rstdb);
    k_snorm<<<dim3(B * F * N / 4 / 256), 256, 0, stream>>>(src, meanb, rstdb, Vb);
    k_adjmsg<<<dim3(N / 64, NCH, B), 256, 0, stream>>>(projb, sqn, Vb, pdmsg, pdeg);
    k_gopconv<F, NCH><<<dim3(N / 64, B), 256, 0, stream>>>(
        Vb, pdmsg, pdeg, w + (size_t)i * F * 2 * F, bw + (size_t)i * F,
        wres + (size_t)i * F * F, bres + (size_t)i * F, dst);
    float* tmp = (float*)src;
    src = dst;
    dst = tmp;
  }

  k_readout<<<dim3(B), 256, 0, stream>>>(src, fcl_w, fcl_b, (float*)d_out);
}